// Round 16
// baseline (840.164 us; speedup 1.0000x reference)
//
#include <hip/hip_runtime.h>
#include <stdint.h>
#include <string.h>
#include <cmath>

// SpikingYOLO round 16: f32 spike planes -- zero-VALU window extraction.
// Numerics BIT-IDENTICAL to R9-R15: conv = kc-384-blocked FMA-sequential f32
// chains, k=(ci,kh,kw) ascending; L2 = in-thread 2 chains (flush at k=384);
// L3 = 3 independent chains as separate blocks, combined fadd(fadd(P1,P2),P3);
// bias after; unfused f32 LIF; alpha=0x3F7383C6 beta=0x3F519857.
// R15 post-mortem: L2 conv is the top dispatch (269us, 57% FMA peak); u8->f32
// extraction burns ~25% of VALU issue. f32 spikes load as float4 -> FMA direct.
// ws ~260MB via aliasing; s2pf zpad runs AFTER L2 conv (overlays dead s1pf).

#define BB 4
#define TT 10

// f32 padded plane geometry: left pad 4 cols, top pad 1 row.
// s1pf: 128x128 -> rows 129, row stride 132 f32, plane 17028 f32 (68112 B)
// s2pf: 64x64   -> rows 65,  row stride 68 f32,  plane 4420 f32  (17680 B)

// ------------------------------------------------ zero the f32 pad borders
template<int RS, int NROWS>
__global__ __launch_bounds__(256) void zpad_f(float* __restrict__ buf) {
    float* p = buf + (size_t)blockIdx.x * (RS * NROWS);
    const float4 z4 = make_float4(0.f, 0.f, 0.f, 0.f);
    for (int i = threadIdx.x; i < NROWS + (RS - 4); i += 256) {
        if (i < NROWS) *(float4*)&p[i * RS] = z4;   // cols 0..3 of every row
        else           p[4 + (i - NROWS)] = 0.f;    // rest of top pad row
    }
}

// ---------------------------------------------------------------- conv1+LIF
// unchanged numerics from R9; writes f32 spikes into padded s1pf layout.
__global__ __launch_bounds__(256) void conv1_lif(
    const float* __restrict__ x,    // [4,2,128,128,10]
    const float* __restrict__ w1,   // [64,2,3,3]
    const float* __restrict__ b1,   // [64]
    float* __restrict__ s1pf,       // padded f32 [40*64][129][132]
    float alpha, float beta)
{
    __shared__ float xs[2][3][10][10];   // [ci][kh][wi][t]
    __shared__ float wsh[18][64];        // [tap][co]
    const int tid = threadIdx.x;
    const int b = blockIdx.z, h = blockIdx.y, w0 = blockIdx.x * 8;

    for (int i = tid; i < 1152; i += 256) {
        int co = i & 63, tap = i >> 6;
        wsh[tap][co] = w1[co * 18 + tap];
    }
    for (int i = tid; i < 600; i += 256) {
        int t = i % 10; int rest = i / 10;
        int wi = rest % 10; rest /= 10;
        int kh = rest % 3; int ci = rest / 3;
        int hh = h - 1 + kh, ww = w0 - 1 + wi;
        float v = 0.f;
        if (hh >= 0 && hh < 128 && ww >= 0 && ww < 128)
            v = x[(((b * 2 + ci) * 128 + hh) * 128 + ww) * 10 + t];
        xs[ci][kh][wi][t] = v;
    }
    __syncthreads();

    const int px  = tid & 7;
    const int cog = (tid >> 3) * 2;
    float acc[2][10];
#pragma unroll
    for (int c = 0; c < 2; ++c)
#pragma unroll
        for (int t = 0; t < 10; ++t) acc[c][t] = 0.f;

#pragma unroll
    for (int tap = 0; tap < 18; ++tap) {
        const int ci = tap / 9, kh = (tap % 9) / 3, kw = tap % 3;
        float2 wv = *(const float2*)&wsh[tap][cog];
#pragma unroll
        for (int t = 0; t < 10; ++t) {
            float xv = xs[ci][kh][px + kw][t];
            acc[0][t] = __fmaf_rn(wv.x, xv, acc[0][t]);
            acc[1][t] = __fmaf_rn(wv.y, xv, acc[1][t]);
        }
    }
#pragma unroll
    for (int c = 0; c < 2; ++c) {
        const float bv = b1[cog + c];
        float syn = 0.f, mem = 0.f;
#pragma unroll
        for (int t = 0; t < 10; ++t) {
            float cur = __fadd_rn(acc[c][t], bv);
            syn = __fadd_rn(__fmul_rn(beta, syn), cur);
            mem = __fadd_rn(__fmul_rn(alpha, mem), syn);
            bool sc = (mem >= 1.0f);
            mem = __fsub_rn(mem, sc ? 1.0f : 0.0f);
            s1pf[(size_t)((t * BB + b) * 64 + (cog + c)) * 17028u
                 + (h + 1) * 132 + (w0 + px + 4)] = sc ? 1.0f : 0.0f;
        }
    }
}

// --------------------------------------------------- weight transpose kernel
__global__ __launch_bounds__(256) void wtrans(
    const float* __restrict__ w, float* __restrict__ wt, int K, int COUT)
{
    int i = blockIdx.x * 256 + threadIdx.x;
    if (i < K * COUT) {
        int k = i / COUT, co = i - k * COUT;
        wt[i] = w[co * K + k];
    }
}

// ---------------------------- per-ci conv taps, f32 input, 8co x 4px
// window img cols 8w4-1..8w4+7 = plane idx 8w4+3..8w4+11; aligned start 8w4.
template<int COUT, int PLANE_F, int RS_F, int KHB, int KHE>
__device__ __forceinline__ void conv_ci8f(
    int ci, const float* __restrict__ fb, const float* __restrict__ wt,
    int cob, const int off[3], float part[32])
{
    const float* p = fb + (uint32_t)ci * PLANE_F;
#pragma unroll
    for (int kh = KHB; kh < KHE; ++kh) {
        const float* q = p + off[kh];
        float4 a = *(const float4*)q;
        float4 bq = *(const float4*)(q + 4);
        float4 cq = *(const float4*)(q + 8);
        float sv[9] = {a.w, bq.x, bq.y, bq.z, bq.w, cq.x, cq.y, cq.z, cq.w};
#pragma unroll
        for (int kw = 0; kw < 3; ++kw) {
            const float* wp = wt + (ci * 9 + kh * 3 + kw) * COUT + cob; // uniform -> s_load
#pragma unroll
            for (int co = 0; co < 8; ++co) {
                const float wv = wp[co];
#pragma unroll
                for (int j = 0; j < 4; ++j)
                    part[co * 4 + j] = __fmaf_rn(wv, sv[2 * j + kw], part[co * 4 + j]);
            }
        }
    }
}

// ---------------------------- per-ci conv taps, f32 input, 16co x 4px
template<int COUT, int PLANE_F, int RS_F, int KHB, int KHE>
__device__ __forceinline__ void conv_ci16f(
    int ci, const float* __restrict__ fb, const float* __restrict__ wt,
    int cob, const int off[3], float part[64])
{
    const float* p = fb + (uint32_t)ci * PLANE_F;
#pragma unroll
    for (int kh = KHB; kh < KHE; ++kh) {
        const float* q = p + off[kh];
        float4 a = *(const float4*)q;
        float4 bq = *(const float4*)(q + 4);
        float4 cq = *(const float4*)(q + 8);
        float sv[9] = {a.w, bq.x, bq.y, bq.z, bq.w, cq.x, cq.y, cq.z, cq.w};
#pragma unroll
        for (int kw = 0; kw < 3; ++kw) {
            const float* wp = wt + (ci * 9 + kh * 3 + kw) * COUT + cob; // uniform -> s_load_dwordx16
#pragma unroll
            for (int co = 0; co < 16; ++co) {
                const float wv = wp[co];
#pragma unroll
                for (int j = 0; j < 4; ++j)
                    part[co * 4 + j] = __fmaf_rn(wv, sv[2 * j + kw], part[co * 4 + j]);
            }
        }
    }
}

// -------------------- L2 conv: in-thread 2 chains, 8co x 4px, f32 input
template<int CIN, int COUT, int HOUT, int WTH, int PLANE_F, int RS_F,
         int F1CI, int F1KH>
__global__ __launch_bounds__(256) void conv_g8f(
    const float* __restrict__ sin,     // padded f32 planes [40*CIN][...]
    const float* __restrict__ wt,      // [CIN*9][COUT] transposed
    float* __restrict__ cur)           // [40,COUT,HOUT,HOUT] pre-bias currents
{
    const int tid = threadIdx.x;
    const int w4  = tid & (WTH - 1);
    const int hh  = blockIdx.x * (256 / WTH) + (tid / WTH);
    const int cob = blockIdx.y * 8;
    const int f   = blockIdx.z;

    const float* fb = sin + (size_t)f * CIN * PLANE_F;
    int off[3];
#pragma unroll
    for (int kh = 0; kh < 3; ++kh) off[kh] = (2 * hh + kh) * RS_F + 8 * w4;

    float part[32], tot[32];
#pragma unroll
    for (int n = 0; n < 32; ++n) { part[n] = 0.f; tot[n] = 0.f; }

    for (int ci = 0; ci < F1CI; ++ci)
        conv_ci8f<COUT,PLANE_F,RS_F,0,3>(ci, fb, wt, cob, off, part);
    // kc flush #1 at global k=384
    conv_ci8f<COUT,PLANE_F,RS_F,0,F1KH>(F1CI, fb, wt, cob, off, part);
#pragma unroll
    for (int n = 0; n < 32; ++n) { tot[n] = __fadd_rn(tot[n], part[n]); part[n] = 0.f; }
    conv_ci8f<COUT,PLANE_F,RS_F,F1KH,3>(F1CI, fb, wt, cob, off, part);
    for (int ci = F1CI + 1; ci < CIN; ++ci)
        conv_ci8f<COUT,PLANE_F,RS_F,0,3>(ci, fb, wt, cob, off, part);

#pragma unroll
    for (int c = 0; c < 8; ++c) {
        float4 v = make_float4(__fadd_rn(tot[c*4+0], part[c*4+0]),
                               __fadd_rn(tot[c*4+1], part[c*4+1]),
                               __fadd_rn(tot[c*4+2], part[c*4+2]),
                               __fadd_rn(tot[c*4+3], part[c*4+3]));
        *(float4*)&cur[((uint32_t)(f * COUT + cob + c) * HOUT + hh) * HOUT + 4 * w4] = v;
    }
}

// ------------------- L3 conv, chain-split (R15), f32 input, 16co x 4px
// chain0: ci 0..41 + ci42 kh{0,1}; chain1: ci42 kh2 + 43..84 + ci85 kh0;
// chain2: ci85 kh{1,2} + 86..127.
__global__ __launch_bounds__(256) void conv3_chains_f(
    const float* __restrict__ sin,     // s2pf padded [40*128][65][68]
    const float* __restrict__ wt,      // [1152][256]
    float* __restrict__ p0, float* __restrict__ p1, float* __restrict__ p2)
{
    const int tid = threadIdx.x;
    const int zc  = blockIdx.z / 40;
    const int f   = blockIdx.z - zc * 40;
    const int w4  = tid & 7;
    const int hh  = tid >> 3;            // 32 rows per block
    const int cob = blockIdx.y * 16;

    const float* fb = sin + (size_t)f * 128 * 4420;
    int off[3];
#pragma unroll
    for (int kh = 0; kh < 3; ++kh) off[kh] = (2 * hh + kh) * 68 + 8 * w4;

    float part[64];
#pragma unroll
    for (int n = 0; n < 64; ++n) part[n] = 0.f;

    float* outp;
    if (zc == 0) {
        for (int ci = 0; ci < 42; ++ci)
            conv_ci16f<256,4420,68,0,3>(ci, fb, wt, cob, off, part);
        conv_ci16f<256,4420,68,0,2>(42, fb, wt, cob, off, part);
        outp = p0;
    } else if (zc == 1) {
        conv_ci16f<256,4420,68,2,3>(42, fb, wt, cob, off, part);
        for (int ci = 43; ci < 85; ++ci)
            conv_ci16f<256,4420,68,0,3>(ci, fb, wt, cob, off, part);
        conv_ci16f<256,4420,68,0,1>(85, fb, wt, cob, off, part);
        outp = p1;
    } else {
        conv_ci16f<256,4420,68,1,3>(85, fb, wt, cob, off, part);
        for (int ci = 86; ci < 128; ++ci)
            conv_ci16f<256,4420,68,0,3>(ci, fb, wt, cob, off, part);
        outp = p2;
    }

#pragma unroll
    for (int c = 0; c < 16; ++c)
        *(float4*)&outp[((uint32_t)(f * 256 + cob + c) * 32 + hh) * 32 + 4 * w4] =
            make_float4(part[c*4+0], part[c*4+1], part[c*4+2], part[c*4+3]);
}

// ------------------------------------------ LIF scan over currents -> spikes
// writes f32 spikes into the PADDED s2pf layout (interior only).
template<int COUT, int HW, int HOUTW, int RS_F, int PLANE_F>
__global__ __launch_bounds__(256) void lif_s(
    const float* __restrict__ cur, const float* __restrict__ bias,
    float* __restrict__ spk_f, float alpha, float beta)
{
    const int px = (blockIdx.x * 256 + threadIdx.x) * 4;
    const int co = blockIdx.y;
    const int b  = blockIdx.z;
    const int h  = px / HOUTW, w = px % HOUTW;
    const float bv = bias[co];
    float syn[4] = {0.f,0.f,0.f,0.f}, mem[4] = {0.f,0.f,0.f,0.f};
    for (int t = 0; t < TT; ++t) {
        const int f = t * BB + b;
        float4 v = *(const float4*)&cur[((uint32_t)(f * COUT + co)) * HW + px];
        const float vv[4] = {v.x, v.y, v.z, v.w};
        float sp[4];
#pragma unroll
        for (int j = 0; j < 4; ++j) {
            float c = __fadd_rn(vv[j], bv);
            syn[j] = __fadd_rn(__fmul_rn(beta, syn[j]), c);
            mem[j] = __fadd_rn(__fmul_rn(alpha, mem[j]), syn[j]);
            bool sc = (mem[j] >= 1.0f);
            sp[j] = sc ? 1.0f : 0.0f;
            mem[j] = __fsub_rn(mem[j], sp[j]);
        }
        *(float4*)&spk_f[(size_t)(f * COUT + co) * PLANE_F + (h + 1) * RS_F + (w + 4)] =
            make_float4(sp[0], sp[1], sp[2], sp[3]);
    }
}

// ---------------------- LIF + time-mean from 3 chain partials (layer 3)
__global__ __launch_bounds__(256) void lif_mean3(
    const float* __restrict__ p0, const float* __restrict__ p1,
    const float* __restrict__ p2, const float* __restrict__ bias,
    float* __restrict__ pooled, float alpha, float beta)
{
    const int px = (blockIdx.x * 256 + threadIdx.x) * 4;
    const int co = blockIdx.y;
    const int b  = blockIdx.z;
    const float bv = bias[co];
    float syn[4] = {0.f,0.f,0.f,0.f}, mem[4] = {0.f,0.f,0.f,0.f};
    float sum[4] = {0.f,0.f,0.f,0.f};
    for (int t = 0; t < TT; ++t) {
        const int idx = ((t * BB + b) * 256 + co) * 1024 + px;
        float4 a = *(const float4*)&p0[idx];
        float4 c = *(const float4*)&p1[idx];
        float4 d = *(const float4*)&p2[idx];
        const float va[4] = {a.x, a.y, a.z, a.w};
        const float vc[4] = {c.x, c.y, c.z, c.w};
        const float vd[4] = {d.x, d.y, d.z, d.w};
#pragma unroll
        for (int j = 0; j < 4; ++j) {
            float conv = __fadd_rn(__fadd_rn(va[j], vc[j]), vd[j]);
            float cu = __fadd_rn(conv, bv);
            syn[j] = __fadd_rn(__fmul_rn(beta, syn[j]), cu);
            mem[j] = __fadd_rn(__fmul_rn(alpha, mem[j]), syn[j]);
            bool sc = (mem[j] >= 1.0f);
            float sp = sc ? 1.0f : 0.0f;
            mem[j] = __fsub_rn(mem[j], sp);
            sum[j] = __fadd_rn(sum[j], sp);
        }
    }
    *(float4*)&pooled[(b * 256 + co) * 1024 + px] =
        make_float4(sum[0] / 10.0f, sum[1] / 10.0f, sum[2] / 10.0f, sum[3] / 10.0f);
}

// ------------------------------------------------------------------ det 1x1
__global__ __launch_bounds__(256) void det_conv(
    const float* __restrict__ pooled, // [4,256,1024]
    const float* __restrict__ wd,     // [255,256]
    const float* __restrict__ bd,     // [255]
    float* __restrict__ out)          // [4,255,1024]
{
    __shared__ float wtl[16][64];
    __shared__ float ps[16][64];
    const int tid = threadIdx.x;
    const int b = blockIdx.z;
    const int o_base = blockIdx.y * 64;
    const int px_base = blockIdx.x * 64;
    const int o_off = (tid >> 4) * 4;
    const int px_off = (tid & 15) * 4;
    float acc[4][4];
#pragma unroll
    for (int c = 0; c < 4; ++c) {
        int o = o_base + o_off + c;
        float bv = (o < 255) ? bd[o] : 0.f;
#pragma unroll
        for (int j = 0; j < 4; ++j) acc[c][j] = bv;
    }
    for (int cc = 0; cc < 16; ++cc) {
        for (int k = tid; k < 1024; k += 256) {
            int o = k & 63, ci = k >> 6;
            wtl[ci][o] = (o_base + o < 255) ? wd[(o_base + o) * 256 + cc * 16 + ci] : 0.f;
            ps[ci][o] = pooled[(b * 256 + cc * 16 + ci) * 1024 + px_base + o];
        }
        __syncthreads();
#pragma unroll
        for (int ci = 0; ci < 16; ++ci) {
            float4 wv = *(const float4*)&wtl[ci][o_off];
            float4 sv = *(const float4*)&ps[ci][px_off];
            acc[0][0] += wv.x * sv.x; acc[0][1] += wv.x * sv.y;
            acc[0][2] += wv.x * sv.z; acc[0][3] += wv.x * sv.w;
            acc[1][0] += wv.y * sv.x; acc[1][1] += wv.y * sv.y;
            acc[1][2] += wv.y * sv.z; acc[1][3] += wv.y * sv.w;
            acc[2][0] += wv.z * sv.x; acc[2][1] += wv.z * sv.y;
            acc[2][2] += wv.z * sv.z; acc[2][3] += wv.z * sv.w;
            acc[3][0] += wv.w * sv.x; acc[3][1] += wv.w * sv.y;
            acc[3][2] += wv.w * sv.z; acc[3][3] += wv.w * sv.w;
        }
        __syncthreads();
    }
#pragma unroll
    for (int c = 0; c < 4; ++c) {
        int o = o_base + o_off + c;
        if (o < 255)
            *(float4*)&out[(b * 255 + o) * 1024 + px_base + px_off] =
                make_float4(acc[c][0], acc[c][1], acc[c][2], acc[c][3]);
    }
}

extern "C" void kernel_launch(void* const* d_in, const int* in_sizes, int n_in,
                              void* d_out, int out_size, void* d_ws, size_t ws_size,
                              hipStream_t stream) {
    const float* x  = (const float*)d_in[0];
    const float* w1 = (const float*)d_in[1];
    const float* b1 = (const float*)d_in[2];
    const float* w2 = (const float*)d_in[3];
    const float* b2 = (const float*)d_in[4];
    const float* w3 = (const float*)d_in[5];
    const float* b3 = (const float*)d_in[6];
    const float* wd = (const float*)d_in[7];
    const float* bd = (const float*)d_in[8];
    float* out = (float*)d_out;

    // ws layout with aliasing (lifetimes; ~260 MB):
    //  region A @ 0, 174,366,720 B:
    //    s1pf f32 [2560][17028]   @ 0            live conv1 -> conv_g8f
    //    s2pf f32 [5120][4420]    @ 0            live zpad(after L2) -> conv3   (90,521,600)
    //    P3c  f32 [40*256*1024]   @ 90,521,600   live conv3 -> lif_mean3        (41,943,040)
    //    pooled f32               @ 132,464,640  live lif_mean3 -> det          (4,194,304)
    //  region B @ 174,366,720, 83,886,080 B:
    //    c2   f32 [40*128*4096]   @ B+0          live conv_g8f -> lif_s
    //    P3a  f32                 @ B+0          live conv3 -> lif_mean3
    //    P3b  f32                 @ B+41,943,040
    //  wt2 @ 258,252,800 (294,912); wt3 @ 258,547,712 (1,179,648); end 259,727,360
    uint8_t* wsb = (uint8_t*)d_ws;
    float* s1pf   = (float*)(wsb + 0);
    float* s2pf   = (float*)(wsb + 0);
    float* p3c    = (float*)(wsb + 90521600u);
    float* pooled = (float*)(wsb + 132464640u);
    float* c2     = (float*)(wsb + 174366720u);
    float* p3a    = (float*)(wsb + 174366720u);
    float* p3b    = (float*)(wsb + 216309760u);
    float* wt2    = (float*)(wsb + 258252800u);
    float* wt3    = (float*)(wsb + 258547712u);

    float alpha, beta;
    { uint32_t ab = 0x3F7383C6u; memcpy(&alpha, &ab, 4); }  // e^-0.05f
    { uint32_t bb = 0x3F519857u; memcpy(&beta,  &bb, 4); }  // e^-0.2f

    wtrans<<<288, 256, 0, stream>>>(w2, wt2, 576, 128);
    wtrans<<<1152, 256, 0, stream>>>(w3, wt3, 1152, 256);
    // pad s1pf, fill interior, L2 conv
    zpad_f<132, 129><<<2560, 256, 0, stream>>>(s1pf);
    conv1_lif<<<dim3(16, 128, 4), 256, 0, stream>>>(x, w1, b1, s1pf, alpha, beta);
    conv_g8f<64, 128, 64, 16, 17028, 132, 42, 2>
        <<<dim3(4, 16, 40), 256, 0, stream>>>(s1pf, wt2, c2);
    // s1pf now dead: pad s2pf (overlays it), LIF L2 -> f32 spikes
    zpad_f<68, 65><<<5120, 256, 0, stream>>>(s2pf);
    lif_s<128, 4096, 64, 68, 4420><<<dim3(4, 128, 4), 256, 0, stream>>>(c2, b2, s2pf, alpha, beta);
    // L3 conv: 3 chains x 40 frames; 16co x 4px; grid (1,16,120)
    conv3_chains_f<<<dim3(1, 16, 120), 256, 0, stream>>>(s2pf, wt3, p3a, p3b, p3c);
    lif_mean3<<<dim3(1, 256, 4), 256, 0, stream>>>(p3a, p3b, p3c, b3, pooled, alpha, beta);
    det_conv<<<dim3(16, 4, 4), 256, 0, stream>>>(pooled, wd, bd, out);
}

// Round 17
// 707.062 us; speedup vs baseline: 1.1882x; 1.1882x over previous
//
#include <hip/hip_runtime.h>
#include <stdint.h>
#include <string.h>
#include <cmath>

// SpikingYOLO round 17: L2 conv -> chain-split 16co x 4px (mirror of R15's
// conv3_chains, the fastest conv shape measured). Numerics BIT-IDENTICAL to
// R9-R16: conv = kc-384-blocked FMA-sequential f32 chains, k=(ci,kh,kw)
// ascending; chains combined fadd(fadd(0,P1),P2)[,P3]; bias after; unfused
// f32 LIF; alpha=0x3F7383C6 beta=0x3F519857. u8 spike planes (R16's f32
// planes regressed: 4x window bytes -> VMEM-bound, VALUBusy 82->58).

#define BB 4
#define TT 10

// padded u8 plane geometry: rows -1..HIN-1 (HIN+1 rows), cols -4..HIN+3 (HIN+8)
// L2 input (s1p): HIN=128: row stride 136 B, plane 129*136 = 17544 B
// L3 input (s2p): HIN=64 : row stride 72 B,  plane 65*72   = 4680 B

// ------------------------------------------------ zero the pad borders
template<int RS_DW, int NROWS>
__global__ __launch_bounds__(256) void zpad(uint32_t* __restrict__ buf) {
    const int plane = blockIdx.x;
    const int j = threadIdx.x;
    uint32_t* p = buf + (size_t)plane * (RS_DW * NROWS);
    if (j < NROWS) p[j * RS_DW] = 0u;                    // cols -4..-1 of every row
    const int k = j - NROWS;
    if (k >= 0 && k < RS_DW - 1) p[k + 1] = 0u;          // rest of top pad row (-1)
}

// ---------------------------------------------------------------- conv1+LIF
// unchanged numerics from R9; writes u8 spikes into padded s1p layout.
__global__ __launch_bounds__(256) void conv1_lif(
    const float* __restrict__ x,    // [4,2,128,128,10]
    const float* __restrict__ w1,   // [64,2,3,3]
    const float* __restrict__ b1,   // [64]
    uint8_t* __restrict__ s1p,      // padded [40*64][129][136]
    float alpha, float beta)
{
    __shared__ float xs[2][3][10][10];   // [ci][kh][wi][t]
    __shared__ float wsh[18][64];        // [tap][co]
    const int tid = threadIdx.x;
    const int b = blockIdx.z, h = blockIdx.y, w0 = blockIdx.x * 8;

    for (int i = tid; i < 1152; i += 256) {
        int co = i & 63, tap = i >> 6;
        wsh[tap][co] = w1[co * 18 + tap];
    }
    for (int i = tid; i < 600; i += 256) {
        int t = i % 10; int rest = i / 10;
        int wi = rest % 10; rest /= 10;
        int kh = rest % 3; int ci = rest / 3;
        int hh = h - 1 + kh, ww = w0 - 1 + wi;
        float v = 0.f;
        if (hh >= 0 && hh < 128 && ww >= 0 && ww < 128)
            v = x[(((b * 2 + ci) * 128 + hh) * 128 + ww) * 10 + t];
        xs[ci][kh][wi][t] = v;
    }
    __syncthreads();

    const int px  = tid & 7;
    const int cog = (tid >> 3) * 2;
    float acc[2][10];
#pragma unroll
    for (int c = 0; c < 2; ++c)
#pragma unroll
        for (int t = 0; t < 10; ++t) acc[c][t] = 0.f;

#pragma unroll
    for (int tap = 0; tap < 18; ++tap) {
        const int ci = tap / 9, kh = (tap % 9) / 3, kw = tap % 3;
        float2 wv = *(const float2*)&wsh[tap][cog];
#pragma unroll
        for (int t = 0; t < 10; ++t) {
            float xv = xs[ci][kh][px + kw][t];
            acc[0][t] = __fmaf_rn(wv.x, xv, acc[0][t]);
            acc[1][t] = __fmaf_rn(wv.y, xv, acc[1][t]);
        }
    }
#pragma unroll
    for (int c = 0; c < 2; ++c) {
        const float bv = b1[cog + c];
        float syn = 0.f, mem = 0.f;
#pragma unroll
        for (int t = 0; t < 10; ++t) {
            float cur = __fadd_rn(acc[c][t], bv);
            syn = __fadd_rn(__fmul_rn(beta, syn), cur);
            mem = __fadd_rn(__fmul_rn(alpha, mem), syn);
            float sp = (mem >= 1.0f) ? 1.0f : 0.0f;
            mem = __fsub_rn(mem, sp);
            s1p[(uint32_t)((t * BB + b) * 64 + (cog + c)) * 17544u
                + (h + 1) * 136 + (w0 + px + 4)] = (uint8_t)sp;
        }
    }
}

// --------------------------------------------------- weight transpose kernel
__global__ __launch_bounds__(256) void wtrans(
    const float* __restrict__ w, float* __restrict__ wt, int K, int COUT)
{
    int i = blockIdx.x * 256 + threadIdx.x;
    if (i < K * COUT) {
        int k = i / COUT, co = i - k * COUT;
        wt[i] = w[co * K + k];
    }
}

// -------------------------------- per-ci conv taps, 16co x 4px (u8 input)
template<int COUT, int PLANE, int KHB, int KHE>
__device__ __forceinline__ void conv_ci16(
    int ci, const uint8_t* __restrict__ fb, const float* __restrict__ wt,
    int cob, const int off[3], float part[64])
{
    const uint8_t* p = fb + (uint32_t)ci * PLANE;
    uint32_t d0[3], d1[3], d2[3];
#pragma unroll
    for (int kh = KHB; kh < KHE; ++kh) {
        const uint8_t* q = p + off[kh];
        uint2 v = *(const uint2*)q;
        d0[kh] = v.x; d1[kh] = v.y;
        d2[kh] = *(const uint32_t*)(q + 8);
    }
#pragma unroll
    for (int kh = KHB; kh < KHE; ++kh) {
        float sv[9];
        sv[0] = (float)(d0[kh] >> 24);
        sv[1] = (float)(d1[kh] & 0xffu);
        sv[2] = (float)((d1[kh] >> 8) & 0xffu);
        sv[3] = (float)((d1[kh] >> 16) & 0xffu);
        sv[4] = (float)(d1[kh] >> 24);
        sv[5] = (float)(d2[kh] & 0xffu);
        sv[6] = (float)((d2[kh] >> 8) & 0xffu);
        sv[7] = (float)((d2[kh] >> 16) & 0xffu);
        sv[8] = (float)(d2[kh] >> 24);
#pragma unroll
        for (int kw = 0; kw < 3; ++kw) {
            const float* wp = wt + (ci * 9 + kh * 3 + kw) * COUT + cob; // uniform -> s_load_dwordx16
#pragma unroll
            for (int co = 0; co < 16; ++co) {
                const float wv = wp[co];
#pragma unroll
                for (int j = 0; j < 4; ++j)
                    part[co * 4 + j] = __fmaf_rn(wv, sv[2 * j + kw], part[co * 4 + j]);
            }
        }
    }
}

// ------------------- L2 conv, chain-split: one block computes ONE chain.
// K=576, split at k=384 (ci=42, kh2): chain0 = ci 0..41 + ci42 kh{0,1};
// chain1 = ci42 kh2 + ci 43..63. 16co x 4px, part[64] only.
__global__ __launch_bounds__(256) void conv2_chains(
    const uint8_t* __restrict__ sin,   // s1p padded [40*64][129][136]
    const float* __restrict__ wt,      // [576][128]
    float* __restrict__ p0, float* __restrict__ p1)
{
    const int tid = threadIdx.x;
    const int zc  = blockIdx.z / 40;
    const int f   = blockIdx.z - zc * 40;
    const int w4  = tid & 15;            // 16 w-groups x 4px = 64 cols
    const int hh  = blockIdx.x * 16 + (tid >> 4);
    const int cob = blockIdx.y * 16;

    const uint8_t* fb = sin + (size_t)f * 64 * 17544;
    int off[3];
#pragma unroll
    for (int kh = 0; kh < 3; ++kh) off[kh] = (2 * hh + kh) * 136 + 8 * w4;

    float part[64];
#pragma unroll
    for (int n = 0; n < 64; ++n) part[n] = 0.f;

    float* outp;
    if (zc == 0) {
        for (int ci = 0; ci < 42; ++ci)
            conv_ci16<128,17544,0,3>(ci, fb, wt, cob, off, part);
        conv_ci16<128,17544,0,2>(42, fb, wt, cob, off, part);
        outp = p0;
    } else {
        conv_ci16<128,17544,2,3>(42, fb, wt, cob, off, part);
        for (int ci = 43; ci < 64; ++ci)
            conv_ci16<128,17544,0,3>(ci, fb, wt, cob, off, part);
        outp = p1;
    }

#pragma unroll
    for (int c = 0; c < 16; ++c)
        *(float4*)&outp[((uint32_t)(f * 128 + cob + c) * 64 + hh) * 64 + 4 * w4] =
            make_float4(part[c*4+0], part[c*4+1], part[c*4+2], part[c*4+3]);
}

// ------------------- L3 conv, chain-split (R15): split at 384 / 768.
// chain0: ci 0..41 + ci42 kh{0,1}; chain1: ci42 kh2 + 43..84 + ci85 kh0;
// chain2: ci85 kh{1,2} + 86..127. 16co x 4px, part[64].
__global__ __launch_bounds__(256) void conv3_chains(
    const uint8_t* __restrict__ sin,   // s2p padded [40*128][65][72]
    const float* __restrict__ wt,      // [1152][256]
    float* __restrict__ p0, float* __restrict__ p1, float* __restrict__ p2)
{
    const int tid = threadIdx.x;
    const int zc  = blockIdx.z / 40;
    const int f   = blockIdx.z - zc * 40;
    const int w4  = tid & 7;
    const int hh  = tid >> 3;            // 32 rows per block
    const int cob = blockIdx.y * 16;

    const uint8_t* fb = sin + (size_t)f * 128 * 4680;
    int off[3];
#pragma unroll
    for (int kh = 0; kh < 3; ++kh) off[kh] = (2 * hh + kh) * 72 + 8 * w4;

    float part[64];
#pragma unroll
    for (int n = 0; n < 64; ++n) part[n] = 0.f;

    float* outp;
    if (zc == 0) {
        for (int ci = 0; ci < 42; ++ci)
            conv_ci16<256,4680,0,3>(ci, fb, wt, cob, off, part);
        conv_ci16<256,4680,0,2>(42, fb, wt, cob, off, part);
        outp = p0;
    } else if (zc == 1) {
        conv_ci16<256,4680,2,3>(42, fb, wt, cob, off, part);
        for (int ci = 43; ci < 85; ++ci)
            conv_ci16<256,4680,0,3>(ci, fb, wt, cob, off, part);
        conv_ci16<256,4680,0,1>(85, fb, wt, cob, off, part);
        outp = p1;
    } else {
        conv_ci16<256,4680,1,3>(85, fb, wt, cob, off, part);
        for (int ci = 86; ci < 128; ++ci)
            conv_ci16<256,4680,0,3>(ci, fb, wt, cob, off, part);
        outp = p2;
    }

#pragma unroll
    for (int c = 0; c < 16; ++c)
        *(float4*)&outp[((uint32_t)(f * 256 + cob + c) * 32 + hh) * 32 + 4 * w4] =
            make_float4(part[c*4+0], part[c*4+1], part[c*4+2], part[c*4+3]);
}

// ---------------------- LIF from 2 chain partials -> u8 spikes (layer 2)
// conv = fadd(fadd(0,P1),P2) == R15's in-thread fadd(tot,part). Bit-exact.
template<int COUT, int HW, int HOUTW, int RS, int PLANE>
__global__ __launch_bounds__(256) void lif_s2(
    const float* __restrict__ pa, const float* __restrict__ pb,
    const float* __restrict__ bias,
    uint8_t* __restrict__ spk_p, float alpha, float beta)
{
    const int px = (blockIdx.x * 256 + threadIdx.x) * 4;
    const int co = blockIdx.y;
    const int b  = blockIdx.z;
    const int h  = px / HOUTW, w = px % HOUTW;
    const float bv = bias[co];
    float syn[4] = {0.f,0.f,0.f,0.f}, mem[4] = {0.f,0.f,0.f,0.f};
    for (int t = 0; t < TT; ++t) {
        const int f = t * BB + b;
        const int idx = ((uint32_t)(f * COUT + co)) * HW + px;
        float4 A = *(const float4*)&pa[idx];
        float4 B = *(const float4*)&pb[idx];
        const float va[4] = {A.x, A.y, A.z, A.w};
        const float vb[4] = {B.x, B.y, B.z, B.w};
        uint32_t pk = 0;
#pragma unroll
        for (int j = 0; j < 4; ++j) {
            float conv = __fadd_rn(__fadd_rn(0.0f, va[j]), vb[j]);
            float c = __fadd_rn(conv, bv);
            syn[j] = __fadd_rn(__fmul_rn(beta, syn[j]), c);
            mem[j] = __fadd_rn(__fmul_rn(alpha, mem[j]), syn[j]);
            bool sc = (mem[j] >= 1.0f);
            mem[j] = __fsub_rn(mem[j], sc ? 1.0f : 0.0f);
            pk |= (sc ? 1u : 0u) << (j * 8);
        }
        *(uint32_t*)&spk_p[(size_t)(f * COUT + co) * PLANE + (h + 1) * RS + (w + 4)] = pk;
    }
}

// ---------------------- LIF + time-mean from 3 chain partials (layer 3)
__global__ __launch_bounds__(256) void lif_mean3(
    const float* __restrict__ p0, const float* __restrict__ p1,
    const float* __restrict__ p2, const float* __restrict__ bias,
    float* __restrict__ pooled, float alpha, float beta)
{
    const int px = (blockIdx.x * 256 + threadIdx.x) * 4;
    const int co = blockIdx.y;
    const int b  = blockIdx.z;
    const float bv = bias[co];
    float syn[4] = {0.f,0.f,0.f,0.f}, mem[4] = {0.f,0.f,0.f,0.f};
    float sum[4] = {0.f,0.f,0.f,0.f};
    for (int t = 0; t < TT; ++t) {
        const int idx = ((t * BB + b) * 256 + co) * 1024 + px;
        float4 a = *(const float4*)&p0[idx];
        float4 c = *(const float4*)&p1[idx];
        float4 d = *(const float4*)&p2[idx];
        const float va[4] = {a.x, a.y, a.z, a.w};
        const float vc[4] = {c.x, c.y, c.z, c.w};
        const float vd[4] = {d.x, d.y, d.z, d.w};
#pragma unroll
        for (int j = 0; j < 4; ++j) {
            float conv = __fadd_rn(__fadd_rn(va[j], vc[j]), vd[j]);
            float cu = __fadd_rn(conv, bv);
            syn[j] = __fadd_rn(__fmul_rn(beta, syn[j]), cu);
            mem[j] = __fadd_rn(__fmul_rn(alpha, mem[j]), syn[j]);
            bool sc = (mem[j] >= 1.0f);
            float sp = sc ? 1.0f : 0.0f;
            mem[j] = __fsub_rn(mem[j], sp);
            sum[j] = __fadd_rn(sum[j], sp);
        }
    }
    *(float4*)&pooled[(b * 256 + co) * 1024 + px] =
        make_float4(sum[0] / 10.0f, sum[1] / 10.0f, sum[2] / 10.0f, sum[3] / 10.0f);
}

// ------------------------------------------------------------------ det 1x1
__global__ __launch_bounds__(256) void det_conv(
    const float* __restrict__ pooled, // [4,256,1024]
    const float* __restrict__ wd,     // [255,256]
    const float* __restrict__ bd,     // [255]
    float* __restrict__ out)          // [4,255,1024]
{
    __shared__ float wtl[16][64];
    __shared__ float ps[16][64];
    const int tid = threadIdx.x;
    const int b = blockIdx.z;
    const int o_base = blockIdx.y * 64;
    const int px_base = blockIdx.x * 64;
    const int o_off = (tid >> 4) * 4;
    const int px_off = (tid & 15) * 4;
    float acc[4][4];
#pragma unroll
    for (int c = 0; c < 4; ++c) {
        int o = o_base + o_off + c;
        float bv = (o < 255) ? bd[o] : 0.f;
#pragma unroll
        for (int j = 0; j < 4; ++j) acc[c][j] = bv;
    }
    for (int cc = 0; cc < 16; ++cc) {
        for (int k = tid; k < 1024; k += 256) {
            int o = k & 63, ci = k >> 6;
            wtl[ci][o] = (o_base + o < 255) ? wd[(o_base + o) * 256 + cc * 16 + ci] : 0.f;
            ps[ci][o] = pooled[(b * 256 + cc * 16 + ci) * 1024 + px_base + o];
        }
        __syncthreads();
#pragma unroll
        for (int ci = 0; ci < 16; ++ci) {
            float4 wv = *(const float4*)&wtl[ci][o_off];
            float4 sv = *(const float4*)&ps[ci][px_off];
            acc[0][0] += wv.x * sv.x; acc[0][1] += wv.x * sv.y;
            acc[0][2] += wv.x * sv.z; acc[0][3] += wv.x * sv.w;
            acc[1][0] += wv.y * sv.x; acc[1][1] += wv.y * sv.y;
            acc[1][2] += wv.y * sv.z; acc[1][3] += wv.y * sv.w;
            acc[2][0] += wv.z * sv.x; acc[2][1] += wv.z * sv.y;
            acc[2][2] += wv.z * sv.z; acc[2][3] += wv.z * sv.w;
            acc[3][0] += wv.w * sv.x; acc[3][1] += wv.w * sv.y;
            acc[3][2] += wv.w * sv.z; acc[3][3] += wv.w * sv.w;
        }
        __syncthreads();
    }
#pragma unroll
    for (int c = 0; c < 4; ++c) {
        int o = o_base + o_off + c;
        if (o < 255)
            *(float4*)&out[(b * 255 + o) * 1024 + px_base + px_off] =
                make_float4(acc[c][0], acc[c][1], acc[c][2], acc[c][3]);
    }
}

extern "C" void kernel_launch(void* const* d_in, const int* in_sizes, int n_in,
                              void* d_out, int out_size, void* d_ws, size_t ws_size,
                              hipStream_t stream) {
    const float* x  = (const float*)d_in[0];
    const float* w1 = (const float*)d_in[1];
    const float* b1 = (const float*)d_in[2];
    const float* w2 = (const float*)d_in[3];
    const float* b2 = (const float*)d_in[4];
    const float* w3 = (const float*)d_in[5];
    const float* b3 = (const float*)d_in[6];
    const float* wd = (const float*)d_in[7];
    const float* bd = (const float*)d_in[8];
    float* out = (float*)d_out;

    // ws layout with aliasing (lifetimes; ~238 MB):
    //   s1p u8 [2560][17544]  @ 256          (44,912,640)  conv1 -> conv2_chains
    //   p3a f32 [40*256*1024] @ 256          (41,943,040)  conv3 -> lif_mean3  (overlays s1p)
    //   p2a f32 [40*128*4096] @ 44,912,896   (83,886,080)  conv2 -> lif_s2
    //   p3b f32               @ 44,912,896   (41,943,040)  conv3 -> lif_mean3  (overlays p2a)
    //   p3c f32               @ 86,855,936   (41,943,040)  conv3 -> lif_mean3  (overlays p2a)
    //   p2b f32               @ 128,798,976  (83,886,080)  conv2 -> lif_s2
    //   pooled f32            @ 128,798,976  (4,194,304)   lif_mean3 -> det    (overlays p2b)
    //   s2p u8 [5120][4680]   @ 212,685,056  (23,961,600)  lif_s2 -> conv3
    //   wt2 f32 [576][128]    @ 236,646,656  (294,912)
    //   wt3 f32 [1152][256]   @ 236,941,568  (1,179,648)   end 238,121,216
    uint8_t* wsb = (uint8_t*)d_ws;
    uint8_t* s1p    = wsb + 256;
    float*   p3a    = (float*)(wsb + 256);
    float*   p2a    = (float*)(wsb + 44912896u);
    float*   p3b    = (float*)(wsb + 44912896u);
    float*   p3c    = (float*)(wsb + 86855936u);
    float*   p2b    = (float*)(wsb + 128798976u);
    float*   pooled = (float*)(wsb + 128798976u);
    uint8_t* s2p    = wsb + 212685056u;
    float*   wt2    = (float*)(wsb + 236646656u);
    float*   wt3    = (float*)(wsb + 236941568u);

    float alpha, beta;
    { uint32_t ab = 0x3F7383C6u; memcpy(&alpha, &ab, 4); }  // e^-0.05f
    { uint32_t bb = 0x3F519857u; memcpy(&beta,  &bb, 4); }  // e^-0.2f

    zpad<34, 129><<<2560, 256, 0, stream>>>((uint32_t*)s1p);
    zpad<18, 65><<<5120, 256, 0, stream>>>((uint32_t*)s2p);
    wtrans<<<288, 256, 0, stream>>>(w2, wt2, 576, 128);
    wtrans<<<1152, 256, 0, stream>>>(w3, wt3, 1152, 256);
    conv1_lif<<<dim3(16, 128, 4), 256, 0, stream>>>(x, w1, b1, s1p, alpha, beta);
    // L2 conv: 2 chains x 40 frames; 16co x 4px; grid (4,8,80)=2560 blocks
    conv2_chains<<<dim3(4, 8, 80), 256, 0, stream>>>(s1p, wt2, p2a, p2b);
    lif_s2<128, 4096, 64, 72, 4680><<<dim3(4, 128, 4), 256, 0, stream>>>(
        p2a, p2b, b2, s2p, alpha, beta);
    // L3 conv: 3 chains x 40 frames; 16co x 4px; grid (1,16,120)=1920 blocks
    conv3_chains<<<dim3(1, 16, 120), 256, 0, stream>>>(s2p, wt3, p3a, p3b, p3c);
    lif_mean3<<<dim3(1, 256, 4), 256, 0, stream>>>(p3a, p3b, p3c, b3, pooled, alpha, beta);
    det_conv<<<dim3(16, 4, 4), 256, 0, stream>>>(pooled, wd, bd, out);
}